// Round 1
// baseline (2526.515 us; speedup 1.0000x reference)
//
#include <hip/hip_runtime.h>
#include <hip/hip_bf16.h>

// ---------------------------------------------------------------------------
// Problem constants (fixed by the reference setup)
// ---------------------------------------------------------------------------
#define N0   1500000
#define N1   200000
#define N2   20000
#define NB   4096
#define D_IN 100
#define D_H  256
#define D_OUT 47

// ---------------------------------------------------------------------------
// Edge aggregation: agg[dst] += x[src], cnt[dst] += 1   (one block per edge)
// ---------------------------------------------------------------------------
__global__ void agg_kernel(const float* __restrict__ xsrc,
                           const int* __restrict__ src,
                           const int* __restrict__ dst,
                           float* __restrict__ agg,
                           float* __restrict__ cnt,
                           int E, int d)
{
    for (int e = blockIdx.x; e < E; e += gridDim.x) {
        int s = src[e];
        int t = dst[e];
        const float* xs = xsrc + (long)s * d;
        float* ag = agg + (long)t * d;
        for (int f = threadIdx.x; f < d; f += blockDim.x)
            atomicAdd(&ag[f], xs[f]);
        if (threadIdx.x == 0)
            atomicAdd(&cnt[t], 1.0f);
    }
}

// agg[row, :] /= max(cnt[row], 1)   (one block per row)
__global__ void mean_div_kernel(float* __restrict__ agg,
                                const float* __restrict__ cnt,
                                int d)
{
    int row = blockIdx.x;
    float inv = 1.0f / fmaxf(cnt[row], 1.0f);
    float* ag = agg + (long)row * d;
    for (int f = threadIdx.x; f < d; f += blockDim.x)
        ag[f] *= inv;
}

// ---------------------------------------------------------------------------
// Fused linear: C[M,N] = act( A1[M,K1] @ W1[K1,N] + A2[M,K2] @ W2[K2,N] + b )
// Tiled f32 GEMM over combined K = K1+K2. 64x64 tile, K-step 32, 4x4/thread.
// ---------------------------------------------------------------------------
#define TM 64
#define TN 64
#define TK 32

__global__ __launch_bounds__(256)
void fused_linear(const float* __restrict__ A1, int K1,
                  const float* __restrict__ A2, int K2,
                  const float* __restrict__ W1,
                  const float* __restrict__ W2,
                  const float* __restrict__ bias,
                  float* __restrict__ C,
                  int M, int N, int do_relu)
{
    __shared__ float As[TK][TM + 1];
    __shared__ float Ws[TK][TN + 1];

    const int row0 = blockIdx.x * TM;
    const int col0 = blockIdx.y * TN;
    const int tid  = threadIdx.x;
    const int ty   = tid / 16;   // 0..15 -> row group
    const int tx   = tid % 16;   // 0..15 -> col group

    const int K = K1 + K2;
    float acc[4][4] = {};

    for (int k0 = 0; k0 < K; k0 += TK) {
        // A tile: TM rows x TK ks
        #pragma unroll
        for (int i = 0; i < (TM * TK) / 256; ++i) {
            int idx = tid + i * 256;
            int r  = idx / TK;
            int kk = idx % TK;
            int gr = row0 + r;
            int gk = k0 + kk;
            float v = 0.0f;
            if (gr < M && gk < K) {
                v = (gk < K1) ? A1[(long)gr * K1 + gk]
                              : A2[(long)gr * K2 + (gk - K1)];
            }
            As[kk][r] = v;
        }
        // W tile: TK ks x TN cols
        #pragma unroll
        for (int i = 0; i < (TK * TN) / 256; ++i) {
            int idx = tid + i * 256;
            int kk = idx / TN;
            int n  = idx % TN;
            int gk = k0 + kk;
            int gn = col0 + n;
            float v = 0.0f;
            if (gk < K && gn < N) {
                v = (gk < K1) ? W1[(long)gk * N + gn]
                              : W2[(long)(gk - K1) * N + gn];
            }
            Ws[kk][n] = v;
        }
        __syncthreads();

        #pragma unroll
        for (int kk = 0; kk < TK; ++kk) {
            float a[4], w[4];
            #pragma unroll
            for (int i = 0; i < 4; ++i) a[i] = As[kk][ty * 4 + i];
            #pragma unroll
            for (int j = 0; j < 4; ++j) w[j] = Ws[kk][tx * 4 + j];
            #pragma unroll
            for (int i = 0; i < 4; ++i)
                #pragma unroll
                for (int j = 0; j < 4; ++j)
                    acc[i][j] += a[i] * w[j];
        }
        __syncthreads();
    }

    #pragma unroll
    for (int i = 0; i < 4; ++i) {
        int gr = row0 + ty * 4 + i;
        if (gr >= M) continue;
        #pragma unroll
        for (int j = 0; j < 4; ++j) {
            int gn = col0 + tx * 4 + j;
            if (gn >= N) continue;
            float v = acc[i][j] + bias[gn];
            if (do_relu) v = fmaxf(v, 0.0f);
            C[(long)gr * N + gn] = v;
        }
    }
}

// ---------------------------------------------------------------------------
// Row-wise log_softmax: one wave (64 lanes) per row, cols <= 64
// ---------------------------------------------------------------------------
__global__ void log_softmax_kernel(const float* __restrict__ in,
                                   float* __restrict__ out,
                                   int rows, int cols)
{
    int wave = (blockIdx.x * blockDim.x + threadIdx.x) / 64;
    int lane = threadIdx.x % 64;
    if (wave >= rows) return;

    const float* r = in + (long)wave * cols;
    float v = (lane < cols) ? r[lane] : -INFINITY;

    float m = v;
    #pragma unroll
    for (int o = 32; o > 0; o >>= 1) m = fmaxf(m, __shfl_xor(m, o));

    float e = (lane < cols) ? __expf(v - m) : 0.0f;
    float s = e;
    #pragma unroll
    for (int o = 32; o > 0; o >>= 1) s += __shfl_xor(s, o);

    float ls = logf(s);
    if (lane < cols)
        out[(long)wave * cols + lane] = v - m - ls;
}

// ---------------------------------------------------------------------------
extern "C" void kernel_launch(void* const* d_in, const int* in_sizes, int n_in,
                              void* d_out, int out_size, void* d_ws, size_t ws_size,
                              hipStream_t stream)
{
    const float* x    = (const float*)d_in[0];
    const int*   src0 = (const int*)d_in[1];
    const int*   dst0 = (const int*)d_in[2];
    const int*   src1 = (const int*)d_in[3];
    const int*   dst1 = (const int*)d_in[4];
    const int*   src2 = (const int*)d_in[5];
    const int*   dst2 = (const int*)d_in[6];
    const float* Wl0  = (const float*)d_in[7];
    const float* Wr0  = (const float*)d_in[8];
    const float* b0   = (const float*)d_in[9];
    const float* Wl1  = (const float*)d_in[10];
    const float* Wr1  = (const float*)d_in[11];
    const float* b1   = (const float*)d_in[12];
    const float* Wl2  = (const float*)d_in[13];
    const float* Wr2  = (const float*)d_in[14];
    const float* b2   = (const float*)d_in[15];
    float* out = (float*)d_out;

    const int E0 = in_sizes[1];
    const int E1 = in_sizes[3];
    const int E2 = in_sizes[5];

    // Workspace layout (all f32)
    float* ws = (float*)d_ws;
    float* agg0 = ws;                              // N1 * D_IN
    float* cnt0 = agg0 + (long)N1 * D_IN;          // N1
    float* h0   = cnt0 + N1;                       // N1 * D_H
    float* agg1 = h0 + (long)N1 * D_H;             // N2 * D_H
    float* cnt1 = agg1 + (long)N2 * D_H;           // N2
    float* h1   = cnt1 + N2;                       // N2 * D_H
    float* agg2 = h1 + (long)N2 * D_H;             // NB * D_H
    float* cnt2 = agg2 + (long)NB * D_H;           // NB
    float* logits = cnt2 + NB;                     // NB * D_OUT

    // Zero the accumulators (poisoned 0xAA; not re-poisoned between replays)
    hipMemsetAsync(agg0, 0, ((long)N1 * D_IN + N1) * sizeof(float), stream);
    hipMemsetAsync(agg1, 0, ((long)N2 * D_H + N2) * sizeof(float), stream);
    hipMemsetAsync(agg2, 0, ((long)NB * D_H + NB) * sizeof(float), stream);

    // ---------------- Layer 0 ----------------
    agg_kernel<<<E0, 128, 0, stream>>>(x, src0, dst0, agg0, cnt0, E0, D_IN);
    mean_div_kernel<<<N1, 128, 0, stream>>>(agg0, cnt0, D_IN);
    {
        dim3 grid((N1 + TM - 1) / TM, D_H / TN);
        fused_linear<<<grid, 256, 0, stream>>>(agg0, D_IN, x, D_IN,
                                               Wl0, Wr0, b0, h0,
                                               N1, D_H, 1);
    }

    // ---------------- Layer 1 ----------------
    agg_kernel<<<E1, 256, 0, stream>>>(h0, src1, dst1, agg1, cnt1, E1, D_H);
    mean_div_kernel<<<N2, 256, 0, stream>>>(agg1, cnt1, D_H);
    {
        dim3 grid((N2 + TM - 1) / TM, D_H / TN);
        fused_linear<<<grid, 256, 0, stream>>>(agg1, D_H, h0, D_H,
                                               Wl1, Wr1, b1, h1,
                                               N2, D_H, 1);
    }

    // ---------------- Layer 2 ----------------
    agg_kernel<<<E2, 256, 0, stream>>>(h1, src2, dst2, agg2, cnt2, E2, D_H);
    mean_div_kernel<<<NB, 256, 0, stream>>>(agg2, cnt2, D_H);
    {
        dim3 grid((NB + TM - 1) / TM, (D_OUT + TN - 1) / TN);
        fused_linear<<<grid, 256, 0, stream>>>(agg2, D_H, h1, D_H,
                                               Wl2, Wr2, b2, logits,
                                               NB, D_OUT, 0);
    }

    // ---------------- log_softmax ----------------
    {
        int waves_per_block = 256 / 64;
        int blocks = (NB + waves_per_block - 1) / waves_per_block;
        log_softmax_kernel<<<blocks, 256, 0, stream>>>(logits, out, NB, D_OUT);
    }
}

// Round 2
// 2154.635 us; speedup vs baseline: 1.1726x; 1.1726x over previous
//
#include <hip/hip_runtime.h>
#include <hip/hip_bf16.h>

// ---------------------------------------------------------------------------
// Problem constants (fixed by the reference setup)
// ---------------------------------------------------------------------------
#define N0   1500000
#define N1   200000
#define N2   20000
#define NB   4096
#define D_IN 100
#define D_H  256
#define D_OUT 47

// ---------------------------------------------------------------------------
// CSR build: histogram -> exclusive scan -> scatter (per launch, deterministic
// up to intra-row edge order; f32 sum-order variance is << tolerance)
// ---------------------------------------------------------------------------
__global__ void hist_kernel(const int* __restrict__ dst, int* __restrict__ deg, int E)
{
    int i = blockIdx.x * blockDim.x + threadIdx.x;
    if (i < E) atomicAdd(&deg[dst[i]], 1);
}

// Single-block blocked exclusive scan over n elements (n up to ~1M fine)
__global__ __launch_bounds__(1024)
void scan_kernel(const int* __restrict__ deg, int* __restrict__ rowstart, int n)
{
    __shared__ int sums[1024];
    const int tid = threadIdx.x;
    const int chunk = (n + 1023) / 1024;
    const int begin = tid * chunk;
    const int end = min(begin + chunk, n);

    int s = 0;
    for (int i = begin; i < end; ++i) s += deg[i];
    sums[tid] = s;
    __syncthreads();

    // Hillis-Steele inclusive scan over the 1024 partial sums
    for (int d = 1; d < 1024; d <<= 1) {
        int val = sums[tid];
        int oth = (tid >= d) ? sums[tid - d] : 0;
        __syncthreads();
        sums[tid] = val + oth;
        __syncthreads();
    }

    int run = (tid > 0) ? sums[tid - 1] : 0;
    for (int i = begin; i < end; ++i) { rowstart[i] = run; run += deg[i]; }
    if (end == n) rowstart[n] = run;   // all covering threads write same total
}

__global__ void scatter_kernel(const int* __restrict__ src,
                               const int* __restrict__ dst,
                               const int* __restrict__ rowstart,
                               int* __restrict__ cursor,
                               int* __restrict__ csr_src, int E)
{
    int i = blockIdx.x * blockDim.x + threadIdx.x;
    if (i < E) {
        int t = dst[i];
        int pos = rowstart[t] + atomicAdd(&cursor[t], 1);
        csr_src[pos] = src[i];
    }
}

// ---------------------------------------------------------------------------
// Gather-side mean: one wave per dst row, lane owns feature cols k*64+lane
// ---------------------------------------------------------------------------
template <int D>
__global__ __launch_bounds__(256)
void csr_gather_mean(const float* __restrict__ x,
                     const int* __restrict__ rowstart,
                     const int* __restrict__ csr_src,
                     float* __restrict__ outm, int nrows)
{
    constexpr int K = (D + 63) / 64;
    const int wid  = (blockIdx.x * blockDim.x + threadIdx.x) >> 6;
    const int lane = threadIdx.x & 63;
    if (wid >= nrows) return;

    const int beg = rowstart[wid];
    const int end = rowstart[wid + 1];

    float acc[K];
    #pragma unroll
    for (int k = 0; k < K; ++k) acc[k] = 0.0f;

    for (int e = beg; e < end; ++e) {
        int s = csr_src[e];
        const float* xs = x + (long)s * D;
        #pragma unroll
        for (int k = 0; k < K; ++k) {
            int f = k * 64 + lane;
            if (f < D) acc[k] += xs[f];
        }
    }

    const float inv = 1.0f / fmaxf((float)(end - beg), 1.0f);
    float* o = outm + (long)wid * D;
    #pragma unroll
    for (int k = 0; k < K; ++k) {
        int f = k * 64 + lane;
        if (f < D) o[f] = acc[k] * inv;
    }
}

// ---------------------------------------------------------------------------
// Fused linear: C[M,N] = act( A1[M,K1] @ W1[K1,N] + A2[M,K2] @ W2[K2,N] + b )
// Tiled f32 GEMM over combined K = K1+K2. 64x64 tile, K-step 32, 4x4/thread.
// ---------------------------------------------------------------------------
#define TM 64
#define TN 64
#define TK 32

__global__ __launch_bounds__(256)
void fused_linear(const float* __restrict__ A1, int K1,
                  const float* __restrict__ A2, int K2,
                  const float* __restrict__ W1,
                  const float* __restrict__ W2,
                  const float* __restrict__ bias,
                  float* __restrict__ C,
                  int M, int N, int do_relu)
{
    __shared__ float As[TK][TM + 1];
    __shared__ float Ws[TK][TN + 1];

    const int row0 = blockIdx.x * TM;
    const int col0 = blockIdx.y * TN;
    const int tid  = threadIdx.x;
    const int ty   = tid / 16;
    const int tx   = tid % 16;

    const int K = K1 + K2;
    float acc[4][4] = {};

    for (int k0 = 0; k0 < K; k0 += TK) {
        #pragma unroll
        for (int i = 0; i < (TM * TK) / 256; ++i) {
            int idx = tid + i * 256;
            int r  = idx / TK;
            int kk = idx % TK;
            int gr = row0 + r;
            int gk = k0 + kk;
            float v = 0.0f;
            if (gr < M && gk < K) {
                v = (gk < K1) ? A1[(long)gr * K1 + gk]
                              : A2[(long)gr * K2 + (gk - K1)];
            }
            As[kk][r] = v;
        }
        #pragma unroll
        for (int i = 0; i < (TK * TN) / 256; ++i) {
            int idx = tid + i * 256;
            int kk = idx / TN;
            int n  = idx % TN;
            int gk = k0 + kk;
            int gn = col0 + n;
            float v = 0.0f;
            if (gk < K && gn < N) {
                v = (gk < K1) ? W1[(long)gk * N + gn]
                              : W2[(long)(gk - K1) * N + gn];
            }
            Ws[kk][n] = v;
        }
        __syncthreads();

        #pragma unroll
        for (int kk = 0; kk < TK; ++kk) {
            float a[4], w[4];
            #pragma unroll
            for (int i = 0; i < 4; ++i) a[i] = As[kk][ty * 4 + i];
            #pragma unroll
            for (int j = 0; j < 4; ++j) w[j] = Ws[kk][tx * 4 + j];
            #pragma unroll
            for (int i = 0; i < 4; ++i)
                #pragma unroll
                for (int j = 0; j < 4; ++j)
                    acc[i][j] += a[i] * w[j];
        }
        __syncthreads();
    }

    #pragma unroll
    for (int i = 0; i < 4; ++i) {
        int gr = row0 + ty * 4 + i;
        if (gr >= M) continue;
        #pragma unroll
        for (int j = 0; j < 4; ++j) {
            int gn = col0 + tx * 4 + j;
            if (gn >= N) continue;
            float v = acc[i][j] + bias[gn];
            if (do_relu) v = fmaxf(v, 0.0f);
            C[(long)gr * N + gn] = v;
        }
    }
}

// ---------------------------------------------------------------------------
// Row-wise log_softmax: one wave (64 lanes) per row, cols <= 64
// ---------------------------------------------------------------------------
__global__ void log_softmax_kernel(const float* __restrict__ in,
                                   float* __restrict__ out,
                                   int rows, int cols)
{
    int wave = (blockIdx.x * blockDim.x + threadIdx.x) / 64;
    int lane = threadIdx.x % 64;
    if (wave >= rows) return;

    const float* r = in + (long)wave * cols;
    float v = (lane < cols) ? r[lane] : -INFINITY;

    float m = v;
    #pragma unroll
    for (int o = 32; o > 0; o >>= 1) m = fmaxf(m, __shfl_xor(m, o));

    float e = (lane < cols) ? __expf(v - m) : 0.0f;
    float s = e;
    #pragma unroll
    for (int o = 32; o > 0; o >>= 1) s += __shfl_xor(s, o);

    float ls = logf(s);
    if (lane < cols)
        out[(long)wave * cols + lane] = v - m - ls;
}

// ---------------------------------------------------------------------------
extern "C" void kernel_launch(void* const* d_in, const int* in_sizes, int n_in,
                              void* d_out, int out_size, void* d_ws, size_t ws_size,
                              hipStream_t stream)
{
    const float* x    = (const float*)d_in[0];
    const int*   src0 = (const int*)d_in[1];
    const int*   dst0 = (const int*)d_in[2];
    const int*   src1 = (const int*)d_in[3];
    const int*   dst1 = (const int*)d_in[4];
    const int*   src2 = (const int*)d_in[5];
    const int*   dst2 = (const int*)d_in[6];
    const float* Wl0  = (const float*)d_in[7];
    const float* Wr0  = (const float*)d_in[8];
    const float* b0   = (const float*)d_in[9];
    const float* Wl1  = (const float*)d_in[10];
    const float* Wr1  = (const float*)d_in[11];
    const float* b1   = (const float*)d_in[12];
    const float* Wl2  = (const float*)d_in[13];
    const float* Wr2  = (const float*)d_in[14];
    const float* b2   = (const float*)d_in[15];
    float* out = (float*)d_out;

    const int E0 = in_sizes[1];
    const int E1 = in_sizes[3];
    const int E2 = in_sizes[5];

    // Workspace layout (f32 / i32)
    float* ws = (float*)d_ws;
    float* agg0 = ws;                              // N1 * D_IN
    float* h0   = agg0 + (long)N1 * D_IN;          // N1 * D_H
    float* agg1 = h0 + (long)N1 * D_H;             // N2 * D_H
    float* h1   = agg1 + (long)N2 * D_H;           // N2 * D_H
    float* agg2 = h1 + (long)N2 * D_H;             // NB * D_H
    float* logits = agg2 + (long)NB * D_H;         // NB * D_OUT

    int* iws      = (int*)(logits + (long)NB * D_OUT);
    int* deg      = iws;                           // N1 (max across layers)
    int* rowstart = deg + N1;                      // N1 + 1
    int* cursor   = rowstart + N1 + 1;             // N1
    int* csr_src  = cursor + N1;                   // E0 (max across layers)

    // ---------------- Layer 0 ----------------
    hipMemsetAsync(deg, 0, N1 * sizeof(int), stream);
    hipMemsetAsync(cursor, 0, N1 * sizeof(int), stream);
    hist_kernel<<<(E0 + 255) / 256, 256, 0, stream>>>(dst0, deg, E0);
    scan_kernel<<<1, 1024, 0, stream>>>(deg, rowstart, N1);
    scatter_kernel<<<(E0 + 255) / 256, 256, 0, stream>>>(src0, dst0, rowstart, cursor, csr_src, E0);
    csr_gather_mean<D_IN><<<(N1 + 3) / 4, 256, 0, stream>>>(x, rowstart, csr_src, agg0, N1);
    {
        dim3 grid((N1 + TM - 1) / TM, D_H / TN);
        fused_linear<<<grid, 256, 0, stream>>>(agg0, D_IN, x, D_IN,
                                               Wl0, Wr0, b0, h0,
                                               N1, D_H, 1);
    }

    // ---------------- Layer 1 ----------------
    hipMemsetAsync(deg, 0, N2 * sizeof(int), stream);
    hipMemsetAsync(cursor, 0, N2 * sizeof(int), stream);
    hist_kernel<<<(E1 + 255) / 256, 256, 0, stream>>>(dst1, deg, E1);
    scan_kernel<<<1, 1024, 0, stream>>>(deg, rowstart, N2);
    scatter_kernel<<<(E1 + 255) / 256, 256, 0, stream>>>(src1, dst1, rowstart, cursor, csr_src, E1);
    csr_gather_mean<D_H><<<(N2 + 3) / 4, 256, 0, stream>>>(h0, rowstart, csr_src, agg1, N2);
    {
        dim3 grid((N2 + TM - 1) / TM, D_H / TN);
        fused_linear<<<grid, 256, 0, stream>>>(agg1, D_H, h0, D_H,
                                               Wl1, Wr1, b1, h1,
                                               N2, D_H, 1);
    }

    // ---------------- Layer 2 ----------------
    hipMemsetAsync(deg, 0, NB * sizeof(int), stream);
    hipMemsetAsync(cursor, 0, NB * sizeof(int), stream);
    hist_kernel<<<(E2 + 255) / 256, 256, 0, stream>>>(dst2, deg, E2);
    scan_kernel<<<1, 1024, 0, stream>>>(deg, rowstart, NB);
    scatter_kernel<<<(E2 + 255) / 256, 256, 0, stream>>>(src2, dst2, rowstart, cursor, csr_src, E2);
    csr_gather_mean<D_H><<<(NB + 3) / 4, 256, 0, stream>>>(h1, rowstart, csr_src, agg2, NB);
    {
        dim3 grid((NB + TM - 1) / TM, (D_OUT + TN - 1) / TN);
        fused_linear<<<grid, 256, 0, stream>>>(agg2, D_H, h1, D_H,
                                               Wl2, Wr2, b2, logits,
                                               NB, D_OUT, 0);
    }

    // ---------------- log_softmax ----------------
    {
        int waves_per_block = 256 / 64;
        int blocks = (NB + waves_per_block - 1) / waves_per_block;
        log_softmax_kernel<<<blocks, 256, 0, stream>>>(logits, out, NB, D_OUT);
    }
}

// Round 3
// 1144.377 us; speedup vs baseline: 2.2078x; 1.8828x over previous
//
#include <hip/hip_runtime.h>
#include <hip/hip_bf16.h>

// ---------------------------------------------------------------------------
// Problem constants (fixed by the reference setup)
// ---------------------------------------------------------------------------
#define N0   1500000
#define N1   200000
#define N2   20000
#define NB   4096
#define D_IN 100
#define D_H  256
#define D_OUT 47

#define K0P  224   // padded K for layer 0 (100+100 -> 224, mult of 32)
#define K12P 512   // K for layers 1/2 (256+256)

typedef __bf16 bf16x8 __attribute__((ext_vector_type(8)));
typedef __bf16 bf16x4 __attribute__((ext_vector_type(4)));
typedef float  f32x4  __attribute__((ext_vector_type(4)));

// ---------------------------------------------------------------------------
// CSR build: histogram -> exclusive scan -> scatter
// ---------------------------------------------------------------------------
__global__ void hist_kernel(const int* __restrict__ dst, int* __restrict__ deg, int E)
{
    int i = blockIdx.x * blockDim.x + threadIdx.x;
    if (i < E) atomicAdd(&deg[dst[i]], 1);
}

__global__ __launch_bounds__(1024)
void scan_kernel(const int* __restrict__ deg, int* __restrict__ rowstart, int n)
{
    __shared__ int sums[1024];
    const int tid = threadIdx.x;
    const int chunk = (n + 1023) / 1024;
    const int begin = tid * chunk;
    const int end = min(begin + chunk, n);

    int s = 0;
    for (int i = begin; i < end; ++i) s += deg[i];
    sums[tid] = s;
    __syncthreads();

    for (int d = 1; d < 1024; d <<= 1) {
        int val = sums[tid];
        int oth = (tid >= d) ? sums[tid - d] : 0;
        __syncthreads();
        sums[tid] = val + oth;
        __syncthreads();
    }

    int run = (tid > 0) ? sums[tid - 1] : 0;
    for (int i = begin; i < end; ++i) { rowstart[i] = run; run += deg[i]; }
    if (end == n) rowstart[n] = run;
}

__global__ void scatter_kernel(const int* __restrict__ src,
                               const int* __restrict__ dst,
                               const int* __restrict__ rowstart,
                               int* __restrict__ cursor,
                               int* __restrict__ csr_src, int E)
{
    int i = blockIdx.x * blockDim.x + threadIdx.x;
    if (i < E) {
        int t = dst[i];
        int pos = rowstart[t] + atomicAdd(&cursor[t], 1);
        csr_src[pos] = src[i];
    }
}

// ---------------------------------------------------------------------------
// Layer-0 gather+pack: A0[row] = [ mean(x[srcs]) (100) | x[row] (100) | 0 pad ]
// One wave per dst row; f32 accumulate, bf16 output.
// ---------------------------------------------------------------------------
__global__ __launch_bounds__(256)
void gather_pack_l0(const float* __restrict__ x,
                    const int* __restrict__ rowstart,
                    const int* __restrict__ csr_src,
                    __bf16* __restrict__ A0, int nrows)
{
    const int wid  = (blockIdx.x * blockDim.x + threadIdx.x) >> 6;
    const int lane = threadIdx.x & 63;
    if (wid >= nrows) return;

    const int beg = rowstart[wid];
    const int end = rowstart[wid + 1];

    float a0 = 0.0f, a1 = 0.0f;
    for (int e = beg; e < end; ++e) {
        const float* xs = x + (long)csr_src[e] * D_IN;
        a0 += xs[lane];
        if (lane < D_IN - 64) a1 += xs[64 + lane];
    }
    const float inv = 1.0f / fmaxf((float)(end - beg), 1.0f);

    __bf16* o = A0 + (long)wid * K0P;
    const float* xd = x + (long)wid * D_IN;

    o[lane] = (__bf16)(a0 * inv);
    o[D_IN + lane] = (__bf16)xd[lane];
    if (lane < D_IN - 64) {
        o[64 + lane] = (__bf16)(a1 * inv);
        o[D_IN + 64 + lane] = (__bf16)xd[64 + lane];
    }
    if (lane < K0P - 2 * D_IN) o[2 * D_IN + lane] = (__bf16)0.0f;
}

// ---------------------------------------------------------------------------
// Layers 1/2 gather+pack (D=256, bf16 input): Ap[row] = [ mean | h[row] ]
// ---------------------------------------------------------------------------
__global__ __launch_bounds__(256)
void gather_pack_h(const __bf16* __restrict__ h,
                   const int* __restrict__ rowstart,
                   const int* __restrict__ csr_src,
                   __bf16* __restrict__ Ap, int nrows)
{
    const int wid  = (blockIdx.x * blockDim.x + threadIdx.x) >> 6;
    const int lane = threadIdx.x & 63;
    if (wid >= nrows) return;

    const int beg = rowstart[wid];
    const int end = rowstart[wid + 1];

    float acc0 = 0, acc1 = 0, acc2 = 0, acc3 = 0;
    for (int e = beg; e < end; ++e) {
        const __bf16* hs = h + (long)csr_src[e] * D_H + lane * 4;
        bf16x4 v = *reinterpret_cast<const bf16x4*>(hs);
        acc0 += (float)v[0]; acc1 += (float)v[1];
        acc2 += (float)v[2]; acc3 += (float)v[3];
    }
    const float inv = 1.0f / fmaxf((float)(end - beg), 1.0f);

    bf16x4 m;
    m[0] = (__bf16)(acc0 * inv); m[1] = (__bf16)(acc1 * inv);
    m[2] = (__bf16)(acc2 * inv); m[3] = (__bf16)(acc3 * inv);
    *reinterpret_cast<bf16x4*>(Ap + (long)wid * K12P + lane * 4) = m;

    bf16x4 own = *reinterpret_cast<const bf16x4*>(h + (long)wid * D_H + lane * 4);
    *reinterpret_cast<bf16x4*>(Ap + (long)wid * K12P + D_H + lane * 4) = own;
}

// ---------------------------------------------------------------------------
// Weight pack: Wp[n][k] = (k<K1 ? Wl[k][n] : k<2K1 ? Wr[k-K1][n] : 0), bf16,
// n >= N -> 0. (B^T layout so GEMM B-fragments are contiguous in K.)
// ---------------------------------------------------------------------------
__global__ void pack_weights(const float* __restrict__ Wl,
                             const float* __restrict__ Wr,
                             __bf16* __restrict__ Wp,
                             int K1, int N, int Kpad)
{
    int n = blockIdx.x;
    for (int k = threadIdx.x; k < Kpad; k += blockDim.x) {
        float v = 0.0f;
        if (n < N) {
            if (k < K1)            v = Wl[(long)k * N + n];
            else if (k < 2 * K1)   v = Wr[(long)(k - K1) * N + n];
        }
        Wp[(long)n * Kpad + k] = (__bf16)v;
    }
}

// ---------------------------------------------------------------------------
// bf16 MFMA GEMM: C[M][Nreal] = act(A[M][K] @ Bt[Npad][K]^T + bias)
// 128x128 tile, BK=32, 4 waves (2x2), each wave 64x64 via 4x4 16x16x32 MFMAs.
// LDS rows padded to 40 elems (80B stride -> 2-way bank aliasing = free).
// ---------------------------------------------------------------------------
#define BM 128
#define BN 128
#define BK 32
#define LDK 40

__global__ __launch_bounds__(256)
void mfma_gemm(const __bf16* __restrict__ A,
               const __bf16* __restrict__ Bt,
               const float* __restrict__ bias,
               __bf16* __restrict__ Cbf,
               float* __restrict__ Cf,
               int M, int K, int Nreal, int relu)
{
    __shared__ __bf16 As[BM * LDK];
    __shared__ __bf16 Bs[BN * LDK];

    const int tid  = threadIdx.x;
    const int lane = tid & 63;
    const int wv   = tid >> 6;
    const int wr   = wv >> 1;
    const int wc   = wv & 1;
    const long row0 = (long)blockIdx.x * BM;
    const int  col0 = blockIdx.y * BN;

    f32x4 acc[4][4] = {};

    for (int k0 = 0; k0 < K; k0 += BK) {
        __syncthreads();
        // stage A and Bt tiles: 512 x 16B chunks each, 2 per thread
        #pragma unroll
        for (int i = 0; i < 2; ++i) {
            int c  = tid + i * 256;
            int r  = c >> 2;            // tile row
            int ko = (c & 3) * 8;       // k element offset
            long gr = row0 + r;
            if (gr > M - 1) gr = M - 1; // clamp (epilogue guards writes)
            *reinterpret_cast<uint4*>(&As[r * LDK + ko]) =
                *reinterpret_cast<const uint4*>(&A[gr * K + k0 + ko]);
            *reinterpret_cast<uint4*>(&Bs[r * LDK + ko]) =
                *reinterpret_cast<const uint4*>(&Bt[(long)(col0 + r) * K + k0 + ko]);
        }
        __syncthreads();

        bf16x8 a[4], b[4];
        #pragma unroll
        for (int mi = 0; mi < 4; ++mi)
            a[mi] = *reinterpret_cast<const bf16x8*>(
                &As[(wr * 64 + mi * 16 + (lane & 15)) * LDK + (lane >> 4) * 8]);
        #pragma unroll
        for (int ni = 0; ni < 4; ++ni)
            b[ni] = *reinterpret_cast<const bf16x8*>(
                &Bs[(wc * 64 + ni * 16 + (lane & 15)) * LDK + (lane >> 4) * 8]);

        #pragma unroll
        for (int mi = 0; mi < 4; ++mi)
            #pragma unroll
            for (int ni = 0; ni < 4; ++ni)
                acc[mi][ni] = __builtin_amdgcn_mfma_f32_16x16x32_bf16(
                    a[mi], b[ni], acc[mi][ni], 0, 0, 0);
    }

    // epilogue: C/D layout col=lane&15, row=(lane>>4)*4+reg
    const int colBase = col0 + wc * 64;
    #pragma unroll
    for (int mi = 0; mi < 4; ++mi) {
        const long rowBase = row0 + wr * 64 + mi * 16 + (lane >> 4) * 4;
        #pragma unroll
        for (int j = 0; j < 4; ++j) {
            long r = rowBase + j;
            if (r >= M) continue;
            #pragma unroll
            for (int ni = 0; ni < 4; ++ni) {
                int cc = colBase + ni * 16 + (lane & 15);
                if (cc >= Nreal) continue;
                float v = acc[mi][ni][j] + bias[cc];
                if (relu) v = fmaxf(v, 0.0f);
                if (Cbf) Cbf[r * Nreal + cc] = (__bf16)v;
                else     Cf [r * Nreal + cc] = v;
            }
        }
    }
}

// ---------------------------------------------------------------------------
// Row-wise log_softmax: one wave per row, cols <= 64
// ---------------------------------------------------------------------------
__global__ void log_softmax_kernel(const float* __restrict__ in,
                                   float* __restrict__ out,
                                   int rows, int cols)
{
    int wave = (blockIdx.x * blockDim.x + threadIdx.x) / 64;
    int lane = threadIdx.x % 64;
    if (wave >= rows) return;

    const float* r = in + (long)wave * cols;
    float v = (lane < cols) ? r[lane] : -INFINITY;

    float m = v;
    #pragma unroll
    for (int o = 32; o > 0; o >>= 1) m = fmaxf(m, __shfl_xor(m, o));

    float e = (lane < cols) ? __expf(v - m) : 0.0f;
    float s = e;
    #pragma unroll
    for (int o = 32; o > 0; o >>= 1) s += __shfl_xor(s, o);

    float ls = logf(s);
    if (lane < cols)
        out[(long)wave * cols + lane] = v - m - ls;
}

// ---------------------------------------------------------------------------
extern "C" void kernel_launch(void* const* d_in, const int* in_sizes, int n_in,
                              void* d_out, int out_size, void* d_ws, size_t ws_size,
                              hipStream_t stream)
{
    const float* x    = (const float*)d_in[0];
    const int*   src0 = (const int*)d_in[1];
    const int*   dst0 = (const int*)d_in[2];
    const int*   src1 = (const int*)d_in[3];
    const int*   dst1 = (const int*)d_in[4];
    const int*   src2 = (const int*)d_in[5];
    const int*   dst2 = (const int*)d_in[6];
    const float* Wl0  = (const float*)d_in[7];
    const float* Wr0  = (const float*)d_in[8];
    const float* b0   = (const float*)d_in[9];
    const float* Wl1  = (const float*)d_in[10];
    const float* Wr1  = (const float*)d_in[11];
    const float* b1   = (const float*)d_in[12];
    const float* Wl2  = (const float*)d_in[13];
    const float* Wr2  = (const float*)d_in[14];
    const float* b2   = (const float*)d_in[15];
    float* out = (float*)d_out;

    const int E0 = in_sizes[1];
    const int E1 = in_sizes[3];
    const int E2 = in_sizes[5];

    // Workspace layout (256B-aligned carve-outs)
    char* wp = (char*)d_ws;
    auto alloc = [&](size_t bytes) -> char* {
        char* p = wp; wp += (bytes + 255) & ~(size_t)255; return p;
    };
    __bf16* A0   = (__bf16*)alloc((size_t)N1 * K0P * 2);   // packed layer-0 A
    __bf16* h0   = (__bf16*)alloc((size_t)N1 * D_H * 2);
    __bf16* A1   = (__bf16*)alloc((size_t)N2 * K12P * 2);
    __bf16* h1   = (__bf16*)alloc((size_t)N2 * D_H * 2);
    __bf16* A2   = (__bf16*)alloc((size_t)NB * K12P * 2);
    float*  logits = (float*)alloc((size_t)NB * D_OUT * 4);
    __bf16* Wp0  = (__bf16*)alloc((size_t)256 * K0P * 2);  // Npad=256
    __bf16* Wp1  = (__bf16*)alloc((size_t)256 * K12P * 2); // Npad=256
    __bf16* Wp2  = (__bf16*)alloc((size_t)128 * K12P * 2); // Npad=128
    int* deg      = (int*)alloc((size_t)N1 * 4);
    int* rowstart = (int*)alloc((size_t)(N1 + 1) * 4);
    int* cursor   = (int*)alloc((size_t)N1 * 4);
    int* csr_src  = (int*)alloc((size_t)E0 * 4);

    // Weight packing (tiny, once per launch)
    pack_weights<<<256, 256, 0, stream>>>(Wl0, Wr0, Wp0, D_IN, D_H, K0P);
    pack_weights<<<256, 256, 0, stream>>>(Wl1, Wr1, Wp1, D_H, D_H, K12P);
    pack_weights<<<128, 256, 0, stream>>>(Wl2, Wr2, Wp2, D_H, D_OUT, K12P);

    // ---------------- Layer 0 ----------------
    hipMemsetAsync(deg, 0, N1 * sizeof(int), stream);
    hipMemsetAsync(cursor, 0, N1 * sizeof(int), stream);
    hist_kernel<<<(E0 + 255) / 256, 256, 0, stream>>>(dst0, deg, E0);
    scan_kernel<<<1, 1024, 0, stream>>>(deg, rowstart, N1);
    scatter_kernel<<<(E0 + 255) / 256, 256, 0, stream>>>(src0, dst0, rowstart, cursor, csr_src, E0);
    gather_pack_l0<<<(N1 + 3) / 4, 256, 0, stream>>>(x, rowstart, csr_src, A0, N1);
    {
        dim3 grid((N1 + BM - 1) / BM, 256 / BN);
        mfma_gemm<<<grid, 256, 0, stream>>>(A0, Wp0, b0, h0, nullptr,
                                            N1, K0P, D_H, 1);
    }

    // ---------------- Layer 1 ----------------
    hipMemsetAsync(deg, 0, N2 * sizeof(int), stream);
    hipMemsetAsync(cursor, 0, N2 * sizeof(int), stream);
    hist_kernel<<<(E1 + 255) / 256, 256, 0, stream>>>(dst1, deg, E1);
    scan_kernel<<<1, 1024, 0, stream>>>(deg, rowstart, N2);
    scatter_kernel<<<(E1 + 255) / 256, 256, 0, stream>>>(src1, dst1, rowstart, cursor, csr_src, E1);
    gather_pack_h<<<(N2 + 3) / 4, 256, 0, stream>>>(h0, rowstart, csr_src, A1, N2);
    {
        dim3 grid((N2 + BM - 1) / BM, 256 / BN);
        mfma_gemm<<<grid, 256, 0, stream>>>(A1, Wp1, b1, h1, nullptr,
                                            N2, K12P, D_H, 1);
    }

    // ---------------- Layer 2 ----------------
    hipMemsetAsync(deg, 0, NB * sizeof(int), stream);
    hipMemsetAsync(cursor, 0, NB * sizeof(int), stream);
    hist_kernel<<<(E2 + 255) / 256, 256, 0, stream>>>(dst2, deg, E2);
    scan_kernel<<<1, 1024, 0, stream>>>(deg, rowstart, NB);
    scatter_kernel<<<(E2 + 255) / 256, 256, 0, stream>>>(src2, dst2, rowstart, cursor, csr_src, E2);
    gather_pack_h<<<(NB + 3) / 4, 256, 0, stream>>>(h1, rowstart, csr_src, A2, NB);
    {
        dim3 grid((NB + BM - 1) / BM, 128 / BN);
        mfma_gemm<<<grid, 256, 0, stream>>>(A2, Wp2, b2, nullptr, logits,
                                            NB, K12P, D_OUT, 0);
    }

    // ---------------- log_softmax ----------------
    {
        int waves_per_block = 256 / 64;
        int blocks = (NB + waves_per_block - 1) / waves_per_block;
        log_softmax_kernel<<<blocks, 256, 0, stream>>>(logits, out, NB, D_OUT);
    }
}

// Round 4
// 985.694 us; speedup vs baseline: 2.5632x; 1.1610x over previous
//
#include <hip/hip_runtime.h>
#include <hip/hip_bf16.h>

// ---------------------------------------------------------------------------
// Problem constants (fixed by the reference setup)
// ---------------------------------------------------------------------------
#define N0   1500000
#define N1   200000
#define N2   20000
#define NB   4096
#define D_IN 100
#define D_H  256
#define D_OUT 47

#define K0P  224   // padded K for layer 0 (100+100 -> 224, mult of 32)
#define K12P 512   // K for layers 1/2 (256+256)

typedef __bf16 bf16x8 __attribute__((ext_vector_type(8)));
typedef __bf16 bf16x4 __attribute__((ext_vector_type(4)));
typedef float  f32x4  __attribute__((ext_vector_type(4)));

// ---------------------------------------------------------------------------
// CSR build: histogram -> exclusive scan -> scatter
// ---------------------------------------------------------------------------
__global__ void hist_kernel(const int* __restrict__ dst, int* __restrict__ deg, int E)
{
    int i = blockIdx.x * blockDim.x + threadIdx.x;
    if (i < E) atomicAdd(&deg[dst[i]], 1);
}

__global__ __launch_bounds__(1024)
void scan_kernel(const int* __restrict__ deg, int* __restrict__ rowstart, int n)
{
    __shared__ int sums[1024];
    const int tid = threadIdx.x;
    const int chunk = (n + 1023) / 1024;
    const int begin = tid * chunk;
    const int end = min(begin + chunk, n);

    int s = 0;
    for (int i = begin; i < end; ++i) s += deg[i];
    sums[tid] = s;
    __syncthreads();

    for (int d = 1; d < 1024; d <<= 1) {
        int val = sums[tid];
        int oth = (tid >= d) ? sums[tid - d] : 0;
        __syncthreads();
        sums[tid] = val + oth;
        __syncthreads();
    }

    int run = (tid > 0) ? sums[tid - 1] : 0;
    for (int i = begin; i < end; ++i) { rowstart[i] = run; run += deg[i]; }
    if (end == n) rowstart[n] = run;
}

__global__ void scatter_kernel(const int* __restrict__ src,
                               const int* __restrict__ dst,
                               const int* __restrict__ rowstart,
                               int* __restrict__ cursor,
                               int* __restrict__ csr_src, int E)
{
    int i = blockIdx.x * blockDim.x + threadIdx.x;
    if (i < E) {
        int t = dst[i];
        int pos = rowstart[t] + atomicAdd(&cursor[t], 1);
        csr_src[pos] = src[i];
    }
}

// ---------------------------------------------------------------------------
// Layer-0 gather+pack: A0[row] = [ mean(x[srcs]) (100) | x[row] (100) | 0 pad ]
// One wave per dst row; lanes 0..49 own float2 feature pairs.
// Edge loop unrolled x4 with independent accumulators for memory-level
// parallelism (latency-bound otherwise: R3 profile 1.6 TB/s, VALU 9%).
// ---------------------------------------------------------------------------
__global__ __launch_bounds__(256)
void gather_pack_l0(const float* __restrict__ x,
                    const int* __restrict__ rowstart,
                    const int* __restrict__ csr_src,
                    __bf16* __restrict__ A0, int nrows)
{
    const int wid  = (blockIdx.x * blockDim.x + threadIdx.x) >> 6;
    const int lane = threadIdx.x & 63;
    if (wid >= nrows) return;

    const int beg = rowstart[wid];
    const int end = rowstart[wid + 1];
    const bool act = lane < D_IN / 2;    // 50 lanes x float2 = 100 floats
    const int f = lane * 2;

    float s0 = 0, s1 = 0, t0 = 0, t1 = 0, u0 = 0, u1 = 0, v0 = 0, v1 = 0;
    int e = beg;
    for (; e + 4 <= end; e += 4) {
        int i0 = csr_src[e];
        int i1 = csr_src[e + 1];
        int i2 = csr_src[e + 2];
        int i3 = csr_src[e + 3];
        if (act) {
            float2 p0 = *reinterpret_cast<const float2*>(x + (long)i0 * D_IN + f);
            float2 p1 = *reinterpret_cast<const float2*>(x + (long)i1 * D_IN + f);
            float2 p2 = *reinterpret_cast<const float2*>(x + (long)i2 * D_IN + f);
            float2 p3 = *reinterpret_cast<const float2*>(x + (long)i3 * D_IN + f);
            s0 += p0.x; s1 += p0.y;
            t0 += p1.x; t1 += p1.y;
            u0 += p2.x; u1 += p2.y;
            v0 += p3.x; v1 += p3.y;
        }
    }
    for (; e < end; ++e) {
        int i0 = csr_src[e];
        if (act) {
            float2 p = *reinterpret_cast<const float2*>(x + (long)i0 * D_IN + f);
            s0 += p.x; s1 += p.y;
        }
    }

    const float inv = 1.0f / fmaxf((float)(end - beg), 1.0f);
    __bf16* o = A0 + (long)wid * K0P;
    const float* xd = x + (long)wid * D_IN;

    if (act) {
        float m0 = ((s0 + t0) + (u0 + v0)) * inv;
        float m1 = ((s1 + t1) + (u1 + v1)) * inv;
        o[f]     = (__bf16)m0;
        o[f + 1] = (__bf16)m1;
        float2 d = *reinterpret_cast<const float2*>(xd + f);
        o[D_IN + f]     = (__bf16)d.x;
        o[D_IN + f + 1] = (__bf16)d.y;
    }
    if (lane < K0P - 2 * D_IN) o[2 * D_IN + lane] = (__bf16)0.0f;
}

// ---------------------------------------------------------------------------
// Layers 1/2 gather+pack (D=256, bf16 input): Ap[row] = [ mean | h[row] ]
// Edge loop unrolled x4 (same MLP-vs-latency argument as layer 0).
// ---------------------------------------------------------------------------
__global__ __launch_bounds__(256)
void gather_pack_h(const __bf16* __restrict__ h,
                   const int* __restrict__ rowstart,
                   const int* __restrict__ csr_src,
                   __bf16* __restrict__ Ap, int nrows)
{
    const int wid  = (blockIdx.x * blockDim.x + threadIdx.x) >> 6;
    const int lane = threadIdx.x & 63;
    if (wid >= nrows) return;

    const int beg = rowstart[wid];
    const int end = rowstart[wid + 1];

    float a[4] = {}, b[4] = {}, c[4] = {}, d[4] = {};
    int e = beg;
    for (; e + 4 <= end; e += 4) {
        int i0 = csr_src[e];
        int i1 = csr_src[e + 1];
        int i2 = csr_src[e + 2];
        int i3 = csr_src[e + 3];
        bf16x4 v0 = *reinterpret_cast<const bf16x4*>(h + (long)i0 * D_H + lane * 4);
        bf16x4 v1 = *reinterpret_cast<const bf16x4*>(h + (long)i1 * D_H + lane * 4);
        bf16x4 v2 = *reinterpret_cast<const bf16x4*>(h + (long)i2 * D_H + lane * 4);
        bf16x4 v3 = *reinterpret_cast<const bf16x4*>(h + (long)i3 * D_H + lane * 4);
        #pragma unroll
        for (int j = 0; j < 4; ++j) {
            a[j] += (float)v0[j]; b[j] += (float)v1[j];
            c[j] += (float)v2[j]; d[j] += (float)v3[j];
        }
    }
    for (; e < end; ++e) {
        bf16x4 v = *reinterpret_cast<const bf16x4*>(h + (long)csr_src[e] * D_H + lane * 4);
        #pragma unroll
        for (int j = 0; j < 4; ++j) a[j] += (float)v[j];
    }

    const float inv = 1.0f / fmaxf((float)(end - beg), 1.0f);
    bf16x4 m;
    #pragma unroll
    for (int j = 0; j < 4; ++j)
        m[j] = (__bf16)(((a[j] + b[j]) + (c[j] + d[j])) * inv);
    *reinterpret_cast<bf16x4*>(Ap + (long)wid * K12P + lane * 4) = m;

    bf16x4 own = *reinterpret_cast<const bf16x4*>(h + (long)wid * D_H + lane * 4);
    *reinterpret_cast<bf16x4*>(Ap + (long)wid * K12P + D_H + lane * 4) = own;
}

// ---------------------------------------------------------------------------
// Weight pack: Wp[n][k] = (k<K1 ? Wl[k][n] : k<2K1 ? Wr[k-K1][n] : 0), bf16.
// ---------------------------------------------------------------------------
__global__ void pack_weights(const float* __restrict__ Wl,
                             const float* __restrict__ Wr,
                             __bf16* __restrict__ Wp,
                             int K1, int N, int Kpad)
{
    int n = blockIdx.x;
    for (int k = threadIdx.x; k < Kpad; k += blockDim.x) {
        float v = 0.0f;
        if (n < N) {
            if (k < K1)            v = Wl[(long)k * N + n];
            else if (k < 2 * K1)   v = Wr[(long)(k - K1) * N + n];
        }
        Wp[(long)n * Kpad + k] = (__bf16)v;
    }
}

// ---------------------------------------------------------------------------
// bf16 MFMA GEMM: C[M][Nreal] = act(A[M][K] @ Bt[Npad][K]^T + bias)
// 128x128 tile, BK=32, 4 waves (2x2), each wave 64x64 via 4x4 16x16x32 MFMAs.
// ---------------------------------------------------------------------------
#define BM 128
#define BN 128
#define BK 32
#define LDK 40

__global__ __launch_bounds__(256)
void mfma_gemm(const __bf16* __restrict__ A,
               const __bf16* __restrict__ Bt,
               const float* __restrict__ bias,
               __bf16* __restrict__ Cbf,
               float* __restrict__ Cf,
               int M, int K, int Nreal, int relu)
{
    __shared__ __bf16 As[BM * LDK];
    __shared__ __bf16 Bs[BN * LDK];

    const int tid  = threadIdx.x;
    const int lane = tid & 63;
    const int wv   = tid >> 6;
    const int wr   = wv >> 1;
    const int wc   = wv & 1;
    const long row0 = (long)blockIdx.x * BM;
    const int  col0 = blockIdx.y * BN;

    f32x4 acc[4][4] = {};

    for (int k0 = 0; k0 < K; k0 += BK) {
        __syncthreads();
        #pragma unroll
        for (int i = 0; i < 2; ++i) {
            int c  = tid + i * 256;
            int r  = c >> 2;
            int ko = (c & 3) * 8;
            long gr = row0 + r;
            if (gr > M - 1) gr = M - 1;
            *reinterpret_cast<uint4*>(&As[r * LDK + ko]) =
                *reinterpret_cast<const uint4*>(&A[gr * K + k0 + ko]);
            *reinterpret_cast<uint4*>(&Bs[r * LDK + ko]) =
                *reinterpret_cast<const uint4*>(&Bt[(long)(col0 + r) * K + k0 + ko]);
        }
        __syncthreads();

        bf16x8 a[4], b[4];
        #pragma unroll
        for (int mi = 0; mi < 4; ++mi)
            a[mi] = *reinterpret_cast<const bf16x8*>(
                &As[(wr * 64 + mi * 16 + (lane & 15)) * LDK + (lane >> 4) * 8]);
        #pragma unroll
        for (int ni = 0; ni < 4; ++ni)
            b[ni] = *reinterpret_cast<const bf16x8*>(
                &Bs[(wc * 64 + ni * 16 + (lane & 15)) * LDK + (lane >> 4) * 8]);

        #pragma unroll
        for (int mi = 0; mi < 4; ++mi)
            #pragma unroll
            for (int ni = 0; ni < 4; ++ni)
                acc[mi][ni] = __builtin_amdgcn_mfma_f32_16x16x32_bf16(
                    a[mi], b[ni], acc[mi][ni], 0, 0, 0);
    }

    const int colBase = col0 + wc * 64;
    #pragma unroll
    for (int mi = 0; mi < 4; ++mi) {
        const long rowBase = row0 + wr * 64 + mi * 16 + (lane >> 4) * 4;
        #pragma unroll
        for (int j = 0; j < 4; ++j) {
            long r = rowBase + j;
            if (r >= M) continue;
            #pragma unroll
            for (int ni = 0; ni < 4; ++ni) {
                int cc = colBase + ni * 16 + (lane & 15);
                if (cc >= Nreal) continue;
                float v = acc[mi][ni][j] + bias[cc];
                if (relu) v = fmaxf(v, 0.0f);
                if (Cbf) Cbf[r * Nreal + cc] = (__bf16)v;
                else     Cf [r * Nreal + cc] = v;
            }
        }
    }
}

// ---------------------------------------------------------------------------
// Row-wise log_softmax: one wave per row, cols <= 64
// ---------------------------------------------------------------------------
__global__ void log_softmax_kernel(const float* __restrict__ in,
                                   float* __restrict__ out,
                                   int rows, int cols)
{
    int wave = (blockIdx.x * blockDim.x + threadIdx.x) / 64;
    int lane = threadIdx.x % 64;
    if (wave >= rows) return;

    const float* r = in + (long)wave * cols;
    float v = (lane < cols) ? r[lane] : -INFINITY;

    float m = v;
    #pragma unroll
    for (int o = 32; o > 0; o >>= 1) m = fmaxf(m, __shfl_xor(m, o));

    float e = (lane < cols) ? __expf(v - m) : 0.0f;
    float s = e;
    #pragma unroll
    for (int o = 32; o > 0; o >>= 1) s += __shfl_xor(s, o);

    float ls = logf(s);
    if (lane < cols)
        out[(long)wave * cols + lane] = v - m - ls;
}

// ---------------------------------------------------------------------------
extern "C" void kernel_launch(void* const* d_in, const int* in_sizes, int n_in,
                              void* d_out, int out_size, void* d_ws, size_t ws_size,
                              hipStream_t stream)
{
    const float* x    = (const float*)d_in[0];
    const int*   src0 = (const int*)d_in[1];
    const int*   dst0 = (const int*)d_in[2];
    const int*   src1 = (const int*)d_in[3];
    const int*   dst1 = (const int*)d_in[4];
    const int*   src2 = (const int*)d_in[5];
    const int*   dst2 = (const int*)d_in[6];
    const float* Wl0  = (const float*)d_in[7];
    const float* Wr0  = (const float*)d_in[8];
    const float* b0   = (const float*)d_in[9];
    const float* Wl1  = (const float*)d_in[10];
    const float* Wr1  = (const float*)d_in[11];
    const float* b1   = (const float*)d_in[12];
    const float* Wl2  = (const float*)d_in[13];
    const float* Wr2  = (const float*)d_in[14];
    const float* b2   = (const float*)d_in[15];
    float* out = (float*)d_out;

    const int E0 = in_sizes[1];
    const int E1 = in_sizes[3];
    const int E2 = in_sizes[5];

    // Workspace layout (256B-aligned carve-outs)
    char* wp = (char*)d_ws;
    auto alloc = [&](size_t bytes) -> char* {
        char* p = wp; wp += (bytes + 255) & ~(size_t)255; return p;
    };
    __bf16* A0   = (__bf16*)alloc((size_t)N1 * K0P * 2);
    __bf16* h0   = (__bf16*)alloc((size_t)N1 * D_H * 2);
    __bf16* A1   = (__bf16*)alloc((size_t)N2 * K12P * 2);
    __bf16* h1   = (__bf16*)alloc((size_t)N2 * D_H * 2);
    __bf16* A2   = (__bf16*)alloc((size_t)NB * K12P * 2);
    float*  logits = (float*)alloc((size_t)NB * D_OUT * 4);
    __bf16* Wp0  = (__bf16*)alloc((size_t)256 * K0P * 2);
    __bf16* Wp1  = (__bf16*)alloc((size_t)256 * K12P * 2);
    __bf16* Wp2  = (__bf16*)alloc((size_t)128 * K12P * 2);
    int* deg      = (int*)alloc((size_t)N1 * 4);
    int* rowstart = (int*)alloc((size_t)(N1 + 1) * 4);
    int* cursor   = (int*)alloc((size_t)N1 * 4);
    int* csr_src  = (int*)alloc((size_t)E0 * 4);

    // Weight packing (tiny, once per launch)
    pack_weights<<<256, 256, 0, stream>>>(Wl0, Wr0, Wp0, D_IN, D_H, K0P);
    pack_weights<<<256, 256, 0, stream>>>(Wl1, Wr1, Wp1, D_H, D_H, K12P);
    pack_weights<<<128, 256, 0, stream>>>(Wl2, Wr2, Wp2, D_H, D_OUT, K12P);

    // ---------------- Layer 0 ----------------
    hipMemsetAsync(deg, 0, N1 * sizeof(int), stream);
    hipMemsetAsync(cursor, 0, N1 * sizeof(int), stream);
    hist_kernel<<<(E0 + 255) / 256, 256, 0, stream>>>(dst0, deg, E0);
    scan_kernel<<<1, 1024, 0, stream>>>(deg, rowstart, N1);
    scatter_kernel<<<(E0 + 255) / 256, 256, 0, stream>>>(src0, dst0, rowstart, cursor, csr_src, E0);
    gather_pack_l0<<<(N1 + 3) / 4, 256, 0, stream>>>(x, rowstart, csr_src, A0, N1);
    {
        dim3 grid((N1 + BM - 1) / BM, 256 / BN);
        mfma_gemm<<<grid, 256, 0, stream>>>(A0, Wp0, b0, h0, nullptr,
                                            N1, K0P, D_H, 1);
    }

    // ---------------- Layer 1 ----------------
    hipMemsetAsync(deg, 0, N2 * sizeof(int), stream);
    hipMemsetAsync(cursor, 0, N2 * sizeof(int), stream);
    hist_kernel<<<(E1 + 255) / 256, 256, 0, stream>>>(dst1, deg, E1);
    scan_kernel<<<1, 1024, 0, stream>>>(deg, rowstart, N2);
    scatter_kernel<<<(E1 + 255) / 256, 256, 0, stream>>>(src1, dst1, rowstart, cursor, csr_src, E1);
    gather_pack_h<<<(N2 + 3) / 4, 256, 0, stream>>>(h0, rowstart, csr_src, A1, N2);
    {
        dim3 grid((N2 + BM - 1) / BM, 256 / BN);
        mfma_gemm<<<grid, 256, 0, stream>>>(A1, Wp1, b1, h1, nullptr,
                                            N2, K12P, D_H, 1);
    }

    // ---------------- Layer 2 ----------------
    hipMemsetAsync(deg, 0, NB * sizeof(int), stream);
    hipMemsetAsync(cursor, 0, NB * sizeof(int), stream);
    hist_kernel<<<(E2 + 255) / 256, 256, 0, stream>>>(dst2, deg, E2);
    scan_kernel<<<1, 1024, 0, stream>>>(deg, rowstart, NB);
    scatter_kernel<<<(E2 + 255) / 256, 256, 0, stream>>>(src2, dst2, rowstart, cursor, csr_src, E2);
    gather_pack_h<<<(NB + 3) / 4, 256, 0, stream>>>(h1, rowstart, csr_src, A2, NB);
    {
        dim3 grid((NB + BM - 1) / BM, 128 / BN);
        mfma_gemm<<<grid, 256, 0, stream>>>(A2, Wp2, b2, nullptr, logits,
                                            NB, K12P, D_OUT, 0);
    }

    // ---------------- log_softmax ----------------
    {
        int waves_per_block = 256 / 64;
        int blocks = (NB + waves_per_block - 1) / waves_per_block;
        log_softmax_kernel<<<blocks, 256, 0, stream>>>(logits, out, NB, D_OUT);
    }
}